// Round 2
// baseline (21516.440 us; speedup 1.0000x reference)
//
#include <hip/hip_runtime.h>
#include <math.h>

// Problem constants (match reference)
#define B_   4096
#define N_   50
#define D_   128
#define DV_  8
#define FS_  4
#define SE_  20
#define NEGV (-1e9f)
#define NP_  51          // padded n-stride for transposed LDS tiles

// ---------- fast math helpers (fp32, abs err ~1e-7 — safe for argmax) ----------
__device__ __forceinline__ float frcp_(float x) { return __builtin_amdgcn_rcpf(x); }
__device__ __forceinline__ float ftanh_(float x) {
    float e = __expf(2.f * x);               // inf-safe: x>>0 -> e=inf -> rcp=0 -> 1
    return 1.f - 2.f * frcp_(e + 1.f);
}
__device__ __forceinline__ float fsig_(float x) {
    return frcp_(1.f + __expf(-x));
}
__device__ __forceinline__ float wsum_(float v) {
#pragma unroll
    for (int m = 1; m < 64; m <<= 1) v += __shfl_xor(v, m);
    return v;
}
__device__ __forceinline__ float wmax_(float v) {
#pragma unroll
    for (int m = 1; m < 64; m <<= 1) v = fmaxf(v, __shfl_xor(v, m));
    return v;
}

// ---------- kernel A: fused projections  e_g/e_p = einsum('de,nbe->bnd', W, cu)+b ----------
// block 256 = (d:128, rq:2); 20 rows staged in LDS per iter; both W streams from L2,
// cu read ONCE for both outputs.
__global__ __launch_bounds__(256) void proj2_kernel(
    const float* __restrict__ Wg, const float* __restrict__ bg,
    const float* __restrict__ Wp, const float* __restrict__ bp,
    const float* __restrict__ cu,    // [N][B][D]
    float* __restrict__ og,          // [B][N][D]
    float* __restrict__ op)          // [B][N][D]
{
    __shared__ __align__(16) float scu[20][128];
    __shared__ float sbg[128], sbp[128];
    const int tid = threadIdx.x;
    if (tid < 128) { sbg[tid] = bg[tid]; sbp[tid] = bp[tid]; }
    const int d  = tid & 127;
    const int rq = tid >> 7;   // 0..1
    const float* wg = Wg + d * 128;
    const float* wp = Wp + d * 128;
    const int r0 = blockIdx.x * 200;
    for (int it = 0; it < 10; ++it) {
        const int rbase = r0 + it * 20;
        __syncthreads();
        for (int i = tid; i < 20 * 128; i += 256) {
            int rr = i >> 7, e = i & 127;
            int r = rbase + rr;
            int b = r / 50, n = r - b * 50;
            scu[rr][e] = cu[((size_t)n * B_ + b) * D_ + e];
        }
        __syncthreads();
        float ag[10], ap[10];
#pragma unroll
        for (int k = 0; k < 10; ++k) { ag[k] = 0.f; ap[k] = 0.f; }
        const int rr0 = rq * 10;
        for (int e = 0; e < 128; e += 4) {
            float4 g4 = *(const float4*)&wg[e];
            float4 p4 = *(const float4*)&wp[e];
#pragma unroll
            for (int k = 0; k < 10; ++k) {
                float4 c4 = *(const float4*)&scu[rr0 + k][e];
                ag[k] += g4.x * c4.x + g4.y * c4.y + g4.z * c4.z + g4.w * c4.w;
                ap[k] += p4.x * c4.x + p4.y * c4.y + p4.z * c4.z + p4.w * c4.w;
            }
        }
        float bgv = sbg[d], bpv = sbp[d];
#pragma unroll
        for (int k = 0; k < 10; ++k) {
            og[(size_t)(rbase + rr0 + k) * D_ + d] = ag[k] + bgv;
            op[(size_t)(rbase + rr0 + k) * D_ + d] = ap[k] + bpv;
        }
    }
}

// ---------- kernel B: persistent decode with LDS-resident e_g/e_p ----------
// G rows per block, 512 threads (8 waves). Dynamic LDS layout (floats):
//   [0:16)      : G ulls (mask) + 3*G ints (prev/last/sel)
//   eg  [G][128][NP_]   transposed: eg[g][d][n]
//   ep  [G][128][NP_]
//   sH,sC,sX [G][128]
//   sGate [G][512]      gates; later [0:128)=qg/qp, [128:256)=gl
//   sRed [8][64]
//   sBias[512], sGbq[128], sPbq[128], sGv[128], sPv[128]
//   sSF [G][4]
template <int G>
__global__ __launch_bounds__(512, (G == 1) ? 4 : 2) void decode_dyn(
    const float* __restrict__ dec_in, const float* __restrict__ h0,
    const float* __restrict__ c0,
    const unsigned char* __restrict__ vmask,
    const int* __restrict__ start_idx,
    const float* __restrict__ V,
    const float* __restrict__ cu,
    const float* __restrict__ start_fea,
    const float* __restrict__ W_ih, const float* __restrict__ W_hh,
    const float* __restrict__ b_ih, const float* __restrict__ b_hh,
    const float* __restrict__ gWq, const float* __restrict__ gbq,
    const float* __restrict__ gv,
    const float* __restrict__ pWq, const float* __restrict__ pbq,
    const float* __restrict__ pv,
    const float* __restrict__ step_table,
    const float* __restrict__ tpW1, const float* __restrict__ tpb1,
    const float* __restrict__ tpW2, const float* __restrict__ tpb2,
    const float* __restrict__ e_gG, const float* __restrict__ e_pG,
    float* __restrict__ outp)
{
    constexpr int WPR = 8 / G;      // waves per row
    constexpr int DR  = 128 / WPR;  // d-range per wave in u-phases
    extern __shared__ float smem[];
    unsigned long long* sMask = (unsigned long long*)smem;          // G
    int* sPrev = (int*)(smem + 2 * G);
    int* sLast = sPrev + G;
    int* sSel  = sLast + G;
    float* eg    = smem + 16;
    float* ep    = eg + G * 128 * NP_;
    float* sH    = ep + G * 128 * NP_;
    float* sC    = sH + G * 128;
    float* sX    = sC + G * 128;
    float* sGate = sX + G * 128;
    float* sRed  = sGate + G * 512;
    float* sBias = sRed + 512;
    float* sGbq  = sBias + 512;
    float* sPbq  = sGbq + 128;
    float* sGv   = sPbq + 128;
    float* sPv   = sGv + 128;
    float* sSF   = sPv + 128;       // [G][4]

    const int tid = threadIdx.x;
    const int b0  = blockIdx.x * G;

    // ---- init: params ----
    {
        sBias[tid] = b_ih[tid] + b_hh[tid];
        int w = tid >> 7, d = tid & 127;
        if (w == 0) sGbq[d] = gbq[d];
        else if (w == 1) sPbq[d] = pbq[d];
        else if (w == 2) sGv[d] = gv[d];
        else sPv[d] = pv[d];
    }
    for (int i = tid; i < G * 128; i += 512) {
        int g = i >> 7, d = i & 127;
        size_t src = (size_t)(b0 + g) * D_ + d;
        sH[i] = h0[src];
        sC[i] = c0[src];
        sX[i] = dec_in[src];
        (void)g; (void)d;
    }
    if (tid < G * FS_) {
        int g = tid >> 2, k = tid & 3;
        sSF[g * 4 + k] = start_fea[(size_t)(b0 + g) * FS_ + k];
    }
    if (tid < G) {
        unsigned long long mk = 0ull;
        const unsigned char* mrow = vmask + (size_t)(b0 + tid) * N_;
        for (int n = 0; n < N_; ++n)
            if (mrow[n]) mk |= (1ull << n);
        sMask[tid] = mk;
        sPrev[tid] = 0;
        sLast[tid] = start_idx[b0 + tid];
    }
    // ---- init: load + transpose e_g/e_p tiles into LDS (once per block) ----
    for (int i = tid; i < G * 50 * 32; i += 512) {
        int g = i / 1600; int r = i - g * 1600;
        int n = r >> 5; int d4 = (r & 31) << 2;
        size_t src = ((size_t)(b0 + g) * N_ + n) * D_ + d4;
        float4 vg = *(const float4*)&e_gG[src];
        float4 vp = *(const float4*)&e_pG[src];
        float* dg = eg + g * (128 * NP_) + n;
        dg[(d4 + 0) * NP_] = vg.x; dg[(d4 + 1) * NP_] = vg.y;
        dg[(d4 + 2) * NP_] = vg.z; dg[(d4 + 3) * NP_] = vg.w;
        float* dp = ep + g * (128 * NP_) + n;
        dp[(d4 + 0) * NP_] = vp.x; dp[(d4 + 1) * NP_] = vp.y;
        dp[(d4 + 2) * NP_] = vp.z; dp[(d4 + 3) * NP_] = vp.w;
    }
    __syncthreads();

    const unsigned long long FULL = (1ull << N_) - 1ull;
    const int w    = tid >> 6;
    const int lane = tid & 63;
    const int gw   = w / WPR;        // row this wave serves in u-phases
    const int qw   = w % WPR;        // d-chunk index

    for (int t = 0; t < N_; ++t) {
        // ---- P0: mask update (consumed after >=1 barrier) ----
        if (tid < G) {
            unsigned long long mk = sMask[tid];
            if (t > 0) mk |= (1ull << sPrev[tid]);
            if ((mk & FULL) == FULL) mk &= ~(1ull << (N_ - 1));
            sMask[tid] = mk;
        }
        // ---- P1: gates = x@W_ih.T + h@W_hh.T + bias;  thread = gate j ----
        {
            const int j = tid;
            const float* wih = W_ih + (size_t)j * 128;
            const float* whh = W_hh + (size_t)j * 128;
            float acc[G];
#pragma unroll
            for (int g = 0; g < G; ++g) acc[g] = 0.f;
            for (int e = 0; e < 128; e += 8) {
                float4 wiA = *(const float4*)&wih[e];
                float4 wiB = *(const float4*)&wih[e + 4];
                float4 whA = *(const float4*)&whh[e];
                float4 whB = *(const float4*)&whh[e + 4];
#pragma unroll
                for (int g = 0; g < G; ++g) {
                    float4 xA = *(const float4*)&sX[g * 128 + e];      // uniform: LDS broadcast
                    float4 xB = *(const float4*)&sX[g * 128 + e + 4];
                    float4 hA = *(const float4*)&sH[g * 128 + e];
                    float4 hB = *(const float4*)&sH[g * 128 + e + 4];
                    acc[g] += wiA.x * xA.x + wiA.y * xA.y + wiA.z * xA.z + wiA.w * xA.w
                            + wiB.x * xB.x + wiB.y * xB.y + wiB.z * xB.z + wiB.w * xB.w
                            + whA.x * hA.x + whA.y * hA.y + whA.z * hA.z + whA.w * hA.w
                            + whB.x * hB.x + whB.y * hB.y + whB.z * hB.z + whB.w * hB.w;
                }
            }
            float bb = sBias[j];
#pragma unroll
            for (int g = 0; g < G; ++g) sGate[g * 512 + j] = acc[g] + bb;
        }
        __syncthreads();

        // ---- P2: LSTM pointwise ----
        if (tid < G * 128) {
            int g = tid >> 7, d = tid & 127;
            float ig = fsig_(sGate[g * 512 + d]);
            float fg = fsig_(sGate[g * 512 + 128 + d]);
            float gg = ftanh_(sGate[g * 512 + 256 + d]);
            float og = fsig_(sGate[g * 512 + 384 + d]);
            float c2 = fg * sC[g * 128 + d] + ig * gg;
            sC[g * 128 + d] = c2;
            sH[g * 128 + d] = og * ftanh_(c2);
        }
        __syncthreads();

        // ---- P3: qg = h2 @ gWq.T + gbq  -> sGate[g*512 + 0:128) ----
        if (tid < G * 128) {
            int g = tid >> 7, d = tid & 127;
            const float* wr = gWq + (size_t)d * 128;
            float a = 0.f;
            for (int e = 0; e < 128; e += 4) {
                float4 w4 = *(const float4*)&wr[e];
                float4 h4 = *(const float4*)&sH[g * 128 + e];
                a += w4.x * h4.x + w4.y * h4.y + w4.z * h4.z + w4.w * h4.w;
            }
            sGate[g * 512 + d] = a + sGbq[d];
        }
        __syncthreads();

        // ---- P4a: glimpse u partials; lane = n, wave covers d-range ----
        {
            float ps = 0.f;
            if (lane < N_) {
                const float* egg = eg + gw * (128 * NP_) + lane;
                const float* qg  = sGate + gw * 512;
                for (int dd = qw * DR; dd < qw * DR + DR; ++dd)
                    ps += sGv[dd] * ftanh_(qg[dd] + egg[dd * NP_]);
            }
            sRed[w * 64 + lane] = ps;
        }
        __syncthreads();

        // ---- P4b: combine + masked softmax weights (one wave per row) ----
        if (qw == 0) {
            float u = 0.f;
#pragma unroll
            for (int qq = 0; qq < WPR; ++qq) u += sRed[(gw * WPR + qq) * 64 + lane];
            const bool act = lane < N_;
            const unsigned long long mk = sMask[gw];
            if (act && ((mk >> lane) & 1ull)) u = NEGV;
            if (!act) u = -__builtin_inff();
            float mx = wmax_(u);
            float ex = act ? __expf(u - mx) : 0.f;
            float s  = wsum_(ex);
            sRed[gw * WPR * 64 + lane] = ex * frcp_(s);
        }
        __syncthreads();

        // ---- P4c: gl_d = sum_n w_n * eg[d][n]  (two waves per row) ----
        if (qw < 2) {
            const int d = qw * 64 + lane;
            const float* egg = eg + gw * (128 * NP_) + d * NP_;
            const float* wn  = sRed + gw * WPR * 64;
            float gl = 0.f;
            for (int n = 0; n < N_; ++n)
                gl += wn[n] * egg[n];      // wn broadcast; egg stride-NP_ conflict-free
            sGate[gw * 512 + 128 + d] = gl;
        }
        __syncthreads();

        // ---- P5: qp = gl @ pWq.T + pbq -> sGate[g*512 + 0:128) ----
        if (tid < G * 128) {
            int g = tid >> 7, d = tid & 127;
            const float* wr = pWq + (size_t)d * 128;
            float a = 0.f;
            for (int e = 0; e < 128; e += 4) {
                float4 w4 = *(const float4*)&wr[e];
                float4 g4 = *(const float4*)&sGate[g * 512 + 128 + e];
                a += w4.x * g4.x + w4.y * g4.y + w4.z * g4.z + w4.w * g4.w;
            }
            sGate[g * 512 + d] = a + sPbq[d];
        }
        __syncthreads();

        // ---- P6a: pointer u partials ----
        {
            float ps = 0.f;
            if (lane < N_) {
                const float* epp = ep + gw * (128 * NP_) + lane;
                const float* qp  = sGate + gw * 512;
                for (int dd = qw * DR; dd < qw * DR + DR; ++dd)
                    ps += sPv[dd] * ftanh_(qp[dd] + epp[dd * NP_]);
            }
            sRed[w * 64 + lane] = ps;
        }
        __syncthreads();

        // ---- P6b: logits, log-softmax, argmax, MLP, outputs (one wave per row) ----
        if (qw == 0) {
            const int g = gw;
            const int b = b0 + g;
            float u = 0.f;
#pragma unroll
            for (int qq = 0; qq < WPR; ++qq) u += sRed[(g * WPR + qq) * 64 + lane];
            const bool act = lane < N_;
            const unsigned long long mk = sMask[g];
            float logit;
            if (!act)                      logit = -__builtin_inff();
            else if ((mk >> lane) & 1ull)  logit = NEGV;
            else                           logit = 10.0f * ftanh_(u);
            float mx = wmax_(logit);
            float ex = act ? __expf(logit - mx) : 0.f;
            float s  = wsum_(ex);
            float lse = mx + __logf(s);
            if (act) outp[(size_t)b * (N_ * N_) + t * N_ + lane] = logit - lse;
            // argmax, first-index tie-break
            float av = logit; int ai = act ? lane : (N_ - 1);
#pragma unroll
            for (int mm = 1; mm < 64; mm <<= 1) {
                float ov = __shfl_xor(av, mm);
                int   oi = __shfl_xor(ai, mm);
                bool take = (ov > av) || (ov == av && oi < ai);
                av = take ? ov : av;
                ai = take ? oi : ai;
            }
            const int idx = ai;
            // time-prediction MLP: lane = hidden unit
            const int lastv = sLast[g];
            const float* Vl = V + ((size_t)b * N_ + lastv) * DV_;
            const float* Vi = V + ((size_t)b * N_ + idx) * DV_;
            float hacc = tpb1[lane];
#pragma unroll
            for (int k = 0; k < 8; ++k)  hacc += Vl[k] * tpW1[k * 64 + lane];
#pragma unroll
            for (int k = 0; k < 8; ++k)  hacc += Vi[k] * tpW1[(8 + k) * 64 + lane];
#pragma unroll
            for (int k = 0; k < 4; ++k)  hacc += sSF[g * 4 + k] * tpW1[(16 + k) * 64 + lane];
#pragma unroll
            for (int k = 0; k < 20; ++k) hacc += step_table[t * SE_ + k] * tpW1[(20 + k) * 64 + lane];
            hacc = fmaxf(hacc, 0.f);
            float pred = wsum_(hacc * tpW2[lane]) + tpb2[0];
            if (lane == 0) {
                outp[(size_t)(B_ * N_) * N_ + (size_t)b * N_ + t]                         = (float)idx;
                outp[(size_t)(B_ * N_) * N_ + (size_t)(B_ * N_) + (size_t)b * N_ + t]     = pred;
                outp[(size_t)(B_ * N_) * N_ + 2 * (size_t)(B_ * N_) + (size_t)b * N_ + t] = pred;
                sPrev[g] = idx;
                sLast[g] = idx;
                sSel[g]  = idx;
            }
        }
        __syncthreads();

        // ---- P7: next decoder input x = cu[sel, b, :] ----
        if (tid < G * 128) {
            int g = tid >> 7, d = tid & 127;
            sX[g * 128 + d] = cu[((size_t)sSel[g] * B_ + (b0 + g)) * D_ + d];
        }
        __syncthreads();
    }
}

static constexpr size_t smem_floats(int G) {
    return 16 + (size_t)G * (2 * 128 * NP_ + 3 * 128 + 512 + 4) + 512 + 512 + 4 * 128;
}

extern "C" void kernel_launch(void* const* d_in, const int* in_sizes, int n_in,
                              void* d_out, int out_size, void* d_ws, size_t ws_size,
                              hipStream_t stream)
{
    const float* dec   = (const float*)d_in[0];
    const float* h0    = (const float*)d_in[1];
    const float* c0    = (const float*)d_in[2];
    const unsigned char* vmask = (const unsigned char*)d_in[3];
    const int*   sidx  = (const int*)d_in[4];
    const float* V     = (const float*)d_in[5];
    const float* cu    = (const float*)d_in[8];
    const float* sfea  = (const float*)d_in[10];
    const float* W_ih  = (const float*)d_in[11];
    const float* W_hh  = (const float*)d_in[12];
    const float* b_ih  = (const float*)d_in[13];
    const float* b_hh  = (const float*)d_in[14];
    const float* gWq   = (const float*)d_in[15];
    const float* gbq   = (const float*)d_in[16];
    const float* gWr   = (const float*)d_in[17];
    const float* gbr   = (const float*)d_in[18];
    const float* gv    = (const float*)d_in[19];
    const float* pWq   = (const float*)d_in[20];
    const float* pbq   = (const float*)d_in[21];
    const float* pWr   = (const float*)d_in[22];
    const float* pbr   = (const float*)d_in[23];
    const float* pv    = (const float*)d_in[24];
    const float* stept = (const float*)d_in[25];
    const float* tpW1  = (const float*)d_in[26];
    const float* tpb1  = (const float*)d_in[27];
    const float* tpW2  = (const float*)d_in[28];
    const float* tpb2  = (const float*)d_in[29];

    float* e_g = (float*)d_ws;                   // [B][N][D] fp32
    float* e_p = e_g + (size_t)B_ * N_ * D_;     // 2 x 104.86 MB of ws

    // Fused precompute of both fixed attention-key sets (cu read once)
    proj2_kernel<<<dim3(1024), 256, 0, stream>>>(gWr, gbr, pWr, pbr, cu, e_g, e_p);

    const size_t BYTES2 = smem_floats(2) * sizeof(float);   // ~117.9 KB
    const size_t BYTES1 = smem_floats(1) * sizeof(float);   // ~62.0 KB

    // Try G=2 (1 block/CU, >64KB dynamic LDS). Fallback to G=1 if unsupported.
    (void)hipFuncSetAttribute((const void*)decode_dyn<2>,
                              hipFuncAttributeMaxDynamicSharedMemorySize, (int)BYTES2);
    int nb = 0;
    hipError_t oe = hipOccupancyMaxActiveBlocksPerMultiprocessor(&nb, decode_dyn<2>, 512, BYTES2);
    (void)hipGetLastError();   // clear any error state from the probe
    if (oe == hipSuccess && nb >= 1) {
        decode_dyn<2><<<dim3(B_ / 2), 512, BYTES2, stream>>>(
            dec, h0, c0, vmask, sidx, V, cu, sfea,
            W_ih, W_hh, b_ih, b_hh, gWq, gbq, gv, pWq, pbq, pv,
            stept, tpW1, tpb1, tpW2, tpb2, e_g, e_p, (float*)d_out);
    } else {
        decode_dyn<1><<<dim3(B_), 512, BYTES1, stream>>>(
            dec, h0, c0, vmask, sidx, V, cu, sfea,
            W_ih, W_hh, b_ih, b_hh, gWq, gbq, gv, pWq, pbq, pv,
            stept, tpW1, tpb1, tpW2, tpb2, e_g, e_p, (float*)d_out);
    }
}

// Round 3
// 13996.324 us; speedup vs baseline: 1.5373x; 1.5373x over previous
//
#include <hip/hip_runtime.h>
#include <math.h>

// Problem constants (match reference)
#define B_   4096
#define N_   50
#define D_   128
#define DV_  8
#define FS_  4
#define SE_  20
#define NEGV (-1e9f)
#define NP_  51          // padded n-stride for transposed LDS e_g tile
#define NT_  64          // padded n-stride for transposed global e_pT

// ---------- fast math helpers (fp32, abs err ~1e-7 — safe for argmax) ----------
__device__ __forceinline__ float frcp_(float x) { return __builtin_amdgcn_rcpf(x); }
__device__ __forceinline__ float ftanh_(float x) {
    float e = __expf(2.f * x);               // inf-safe: x>>0 -> e=inf -> rcp=0 -> 1
    return 1.f - 2.f * frcp_(e + 1.f);
}
__device__ __forceinline__ float fsig_(float x) {
    return frcp_(1.f + __expf(-x));
}
__device__ __forceinline__ float wsum_(float v) {
#pragma unroll
    for (int m = 1; m < 64; m <<= 1) v += __shfl_xor(v, m);
    return v;
}
__device__ __forceinline__ float wmax_(float v) {
#pragma unroll
    for (int m = 1; m < 64; m <<= 1) v = fmaxf(v, __shfl_xor(v, m));
    return v;
}

// ---------- kernel A (round-1 proven): e = einsum('de,nbe->bnd', W, cu)+b -> [B][N][D] ----------
__global__ __launch_bounds__(256) void proj_kernel(
    const float* __restrict__ W,     // [128][128]
    const float* __restrict__ bias,  // [128]
    const float* __restrict__ cu,    // [N][B][D]
    float* __restrict__ outp)        // [B][N][D] (row r = b*N+n)
{
    __shared__ __align__(16) float scu[20][128];
    __shared__ float sb[128];
    const int tid = threadIdx.x;
    if (tid < 128) sb[tid] = bias[tid];
    const int d  = tid & 127;
    const int rq = tid >> 7;   // 0..1
    const float* wrow = W + d * 128;
    const int r0 = blockIdx.x * 200;
    for (int it = 0; it < 10; ++it) {
        const int rbase = r0 + it * 20;
        __syncthreads();
        for (int i = tid; i < 20 * 128; i += 256) {
            int rr = i >> 7, e = i & 127;
            int r = rbase + rr;
            int b = r / 50, n = r - b * 50;
            scu[rr][e] = cu[((size_t)n * B_ + b) * D_ + e];
        }
        __syncthreads();
        float acc[10];
#pragma unroll
        for (int k = 0; k < 10; ++k) acc[k] = 0.f;
        const int rr0 = rq * 10;
        for (int e = 0; e < 128; e += 4) {
            float4 w4 = *(const float4*)&wrow[e];
#pragma unroll
            for (int k = 0; k < 10; ++k) {
                float4 c4 = *(const float4*)&scu[rr0 + k][e];   // wave-uniform: LDS broadcast
                acc[k] += w4.x * c4.x + w4.y * c4.y + w4.z * c4.z + w4.w * c4.w;
            }
        }
        float bv = sb[d];
#pragma unroll
        for (int k = 0; k < 10; ++k)
            outp[(size_t)(rbase + rr0 + k) * D_ + d] = acc[k] + bv;   // coalesced over d
    }
}

// ---------- kernel A': same math, TRANSPOSED store -> e_pT[b][d][NT_] ----------
__global__ __launch_bounds__(256) void projT_kernel(
    const float* __restrict__ W,
    const float* __restrict__ bias,
    const float* __restrict__ cu,
    float* __restrict__ outT)        // [B][128][NT_]
{
    __shared__ __align__(16) float scu[20][128];
    __shared__ float sb[128];
    const int tid = threadIdx.x;
    if (tid < 128) sb[tid] = bias[tid];
    const int d  = tid & 127;
    const int rq = tid >> 7;
    const float* wrow = W + d * 128;
    const int r0 = blockIdx.x * 200;
    for (int it = 0; it < 10; ++it) {
        const int rbase = r0 + it * 20;
        __syncthreads();
        for (int i = tid; i < 20 * 128; i += 256) {
            int rr = i >> 7, e = i & 127;
            int r = rbase + rr;
            int b = r / 50, n = r - b * 50;
            scu[rr][e] = cu[((size_t)n * B_ + b) * D_ + e];
        }
        __syncthreads();
        float acc[10];
#pragma unroll
        for (int k = 0; k < 10; ++k) acc[k] = 0.f;
        const int rr0 = rq * 10;
        for (int e = 0; e < 128; e += 4) {
            float4 w4 = *(const float4*)&wrow[e];
#pragma unroll
            for (int k = 0; k < 10; ++k) {
                float4 c4 = *(const float4*)&scu[rr0 + k][e];
                acc[k] += w4.x * c4.x + w4.y * c4.y + w4.z * c4.z + w4.w * c4.w;
            }
        }
        float bv = sb[d];
#pragma unroll
        for (int k = 0; k < 10; ++k) {
            int r = rbase + rr0 + k;
            int b = r / 50, n = r - b * 50;
            // per-thread: n advances by 1 across k -> stays within 1-2 cache lines
            outT[((size_t)b * 128 + d) * NT_ + n] = acc[k] + bv;
        }
    }
}

// ---------- kernel B: persistent decode; G=2 rows/block, 512 thr, 2 blocks/CU ----------
// LDS (floats): hdr 16 | eg [2][128][NP_] | sH/sC/sX [2][128] | sGate [2][512]
//               sRed [8][64] | sBias[512] | sGbq/sPbq/sGv/sPv [128] | sSF [2][4]
// = 16408 floats = 65,632 B  -> 2 blocks/CU on 160KB LDS.
__global__ __launch_bounds__(512, 4) void decode_g2(
    const float* __restrict__ dec_in, const float* __restrict__ h0,
    const float* __restrict__ c0,
    const unsigned char* __restrict__ vmask,
    const int* __restrict__ start_idx,
    const float* __restrict__ V,
    const float* __restrict__ cu,
    const float* __restrict__ start_fea,
    const float* __restrict__ W_ih, const float* __restrict__ W_hh,
    const float* __restrict__ b_ih, const float* __restrict__ b_hh,
    const float* __restrict__ gWq, const float* __restrict__ gbq,
    const float* __restrict__ gv,
    const float* __restrict__ pWq, const float* __restrict__ pbq,
    const float* __restrict__ pv,
    const float* __restrict__ step_table,
    const float* __restrict__ tpW1, const float* __restrict__ tpb1,
    const float* __restrict__ tpW2, const float* __restrict__ tpb2,
    const float* __restrict__ e_gG,   // [B][N][D]
    const float* __restrict__ e_pT,   // [B][128][NT_]
    float* __restrict__ outp)
{
    extern __shared__ float smem[];
    unsigned long long* sMask = (unsigned long long*)smem;   // 2
    int* sPrev = (int*)(smem + 4);                           // 2
    int* sLast = sPrev + 2;                                  // 2
    float* eg    = smem + 16;          // 2*128*51 = 13056
    float* sH    = eg + 13056;         // 256
    float* sC    = sH + 256;
    float* sX    = sC + 256;
    float* sGate = sX + 256;           // 1024
    float* sRed  = sGate + 1024;       // 512
    float* sBias = sRed + 512;         // 512
    float* sGbq  = sBias + 512;
    float* sPbq  = sGbq + 128;
    float* sGv   = sPbq + 128;
    float* sPv   = sGv + 128;
    float* sSF   = sPv + 128;          // [2][4]

    const int tid = threadIdx.x;
    const int b0  = blockIdx.x * 2;

    // ---- init: params + state ----
    {
        sBias[tid] = b_ih[tid] + b_hh[tid];
        int w = tid >> 7, d = tid & 127;
        if (w == 0) sGbq[d] = gbq[d];
        else if (w == 1) sPbq[d] = pbq[d];
        else if (w == 2) sGv[d] = gv[d];
        else sPv[d] = pv[d];
    }
    if (tid < 256) {
        size_t src = (size_t)(b0 + (tid >> 7)) * D_ + (tid & 127);
        sH[tid] = h0[src];
        sC[tid] = c0[src];
        sX[tid] = dec_in[src];
    }
    if (tid < 2 * FS_) {
        int g = tid >> 2, k = tid & 3;
        sSF[g * 4 + k] = start_fea[(size_t)(b0 + g) * FS_ + k];
    }
    if (tid < 2) {
        unsigned long long mk = 0ull;
        const unsigned char* mrow = vmask + (size_t)(b0 + tid) * N_;
        for (int n = 0; n < N_; ++n)
            if (mrow[n]) mk |= (1ull << n);
        sMask[tid] = mk;
        sPrev[tid] = 0;
        sLast[tid] = start_idx[b0 + tid];
    }
    // ---- init: load + transpose e_g into LDS (once per block) ----
    for (int i = tid; i < 2 * 50 * 32; i += 512) {
        int g = i / 1600; int r = i - g * 1600;
        int n = r >> 5; int d4 = (r & 31) << 2;
        float4 vg = *(const float4*)&e_gG[((size_t)(b0 + g) * N_ + n) * D_ + d4];
        float* dg = eg + g * (128 * NP_) + n;
        dg[(d4 + 0) * NP_] = vg.x; dg[(d4 + 1) * NP_] = vg.y;
        dg[(d4 + 2) * NP_] = vg.z; dg[(d4 + 3) * NP_] = vg.w;
    }
    __syncthreads();

    const unsigned long long FULL = (1ull << N_) - 1ull;
    const int w    = tid >> 6;       // wave 0..7
    const int lane = tid & 63;
    const int gw   = w >> 2;         // row this wave serves (4 waves/row)
    const int qw   = w & 3;          // d-chunk index (32 d's each)

    for (int t = 0; t < N_; ++t) {
        // ---- P0: mask update (consumed after >=1 barrier) ----
        if (tid < 2) {
            unsigned long long mk = sMask[tid];
            if (t > 0) mk |= (1ull << sPrev[tid]);
            if ((mk & FULL) == FULL) mk &= ~(1ull << (N_ - 1));
            sMask[tid] = mk;
        }
        // ---- P1: gates = x@W_ih.T + h@W_hh.T + bias; thread = gate row j ----
        {
            const int j = tid;
            const float* wih = W_ih + (size_t)j * 128;
            const float* whh = W_hh + (size_t)j * 128;
            float a0 = 0.f, a1 = 0.f;
            for (int e = 0; e < 128; e += 8) {
                float4 wiA = *(const float4*)&wih[e];
                float4 wiB = *(const float4*)&wih[e + 4];
                float4 whA = *(const float4*)&whh[e];
                float4 whB = *(const float4*)&whh[e + 4];
#pragma unroll
                for (int g = 0; g < 2; ++g) {
                    float4 xA = *(const float4*)&sX[g * 128 + e];      // uniform: broadcast
                    float4 xB = *(const float4*)&sX[g * 128 + e + 4];
                    float4 hA = *(const float4*)&sH[g * 128 + e];
                    float4 hB = *(const float4*)&sH[g * 128 + e + 4];
                    float s = wiA.x * xA.x + wiA.y * xA.y + wiA.z * xA.z + wiA.w * xA.w
                            + wiB.x * xB.x + wiB.y * xB.y + wiB.z * xB.z + wiB.w * xB.w
                            + whA.x * hA.x + whA.y * hA.y + whA.z * hA.z + whA.w * hA.w
                            + whB.x * hB.x + whB.y * hB.y + whB.z * hB.z + whB.w * hB.w;
                    if (g == 0) a0 += s; else a1 += s;
                }
            }
            float bb = sBias[j];
            sGate[j]       = a0 + bb;
            sGate[512 + j] = a1 + bb;
        }
        __syncthreads();

        // ---- P2: LSTM pointwise ----
        if (tid < 256) {
            int g = tid >> 7, d = tid & 127;
            float ig = fsig_(sGate[g * 512 + d]);
            float fg = fsig_(sGate[g * 512 + 128 + d]);
            float gg = ftanh_(sGate[g * 512 + 256 + d]);
            float og = fsig_(sGate[g * 512 + 384 + d]);
            float c2 = fg * sC[tid] + ig * gg;
            sC[tid] = c2;
            sH[tid] = og * ftanh_(c2);
        }
        __syncthreads();

        // ---- P3: qg = h2 @ gWq.T + gbq  -> sGate[g*512 + 0:128) ----
        if (tid < 256) {
            int g = tid >> 7, d = tid & 127;
            const float* wr = gWq + (size_t)d * 128;
            float a = 0.f;
            for (int e = 0; e < 128; e += 4) {
                float4 w4 = *(const float4*)&wr[e];
                float4 h4 = *(const float4*)&sH[g * 128 + e];
                a += w4.x * h4.x + w4.y * h4.y + w4.z * h4.z + w4.w * h4.w;
            }
            sGate[g * 512 + d] = a + sGbq[d];
        }
        __syncthreads();

        // ---- P4a: glimpse u partials; lane = n, wave covers 32 d's ----
        {
            float ps0 = 0.f, ps1 = 0.f;
            if (lane < N_) {
                const float* egg = eg + gw * (128 * NP_) + lane;
                const float* qg  = sGate + gw * 512;
                const int dd0 = qw * 32;
                for (int i = 0; i < 32; i += 2) {
                    ps0 += sGv[dd0 + i]     * ftanh_(qg[dd0 + i]     + egg[(dd0 + i) * NP_]);
                    ps1 += sGv[dd0 + i + 1] * ftanh_(qg[dd0 + i + 1] + egg[(dd0 + i + 1) * NP_]);
                }
            }
            sRed[w * 64 + lane] = ps0 + ps1;
        }
        __syncthreads();

        // ---- P4b: combine + masked softmax weights (one wave per row) ----
        if (qw == 0) {
            float u = sRed[(gw * 4) * 64 + lane] + sRed[(gw * 4 + 1) * 64 + lane]
                    + sRed[(gw * 4 + 2) * 64 + lane] + sRed[(gw * 4 + 3) * 64 + lane];
            const bool act = lane < N_;
            const unsigned long long mk = sMask[gw];
            if (act && ((mk >> lane) & 1ull)) u = NEGV;
            if (!act) u = -__builtin_inff();
            float mx = wmax_(u);
            float ex = act ? __expf(u - mx) : 0.f;
            float s  = wsum_(ex);
            sRed[gw * 4 * 64 + lane] = ex * frcp_(s);
        }
        __syncthreads();

        // ---- P4c: gl_d = sum_n w_n * eg[d][n]  (two waves per row) ----
        if (qw < 2) {
            const int d = qw * 64 + lane;
            const float* egg = eg + gw * (128 * NP_) + d * NP_;
            const float* wn  = sRed + gw * 4 * 64;
            float gl0 = 0.f, gl1 = 0.f;
            for (int n = 0; n < N_; n += 2) {
                gl0 += wn[n] * egg[n];
                gl1 += wn[n + 1] * egg[n + 1];
            }
            sGate[gw * 512 + 128 + d] = gl0 + gl1;
        }
        __syncthreads();

        // ---- P5: qp = gl @ pWq.T + pbq -> sGate[g*512 + 0:128) ----
        if (tid < 256) {
            int g = tid >> 7, d = tid & 127;
            const float* wr = pWq + (size_t)d * 128;
            float a = 0.f;
            for (int e = 0; e < 128; e += 4) {
                float4 w4 = *(const float4*)&wr[e];
                float4 g4 = *(const float4*)&sGate[g * 512 + 128 + e];
                a += w4.x * g4.x + w4.y * g4.y + w4.z * g4.z + w4.w * g4.w;
            }
            sGate[g * 512 + d] = a + sPbq[d];
        }
        __syncthreads();

        // ---- P6a: pointer u partials; e_p streamed from global (L2-resident, coalesced) ----
        {
            float ps0 = 0.f, ps1 = 0.f;
            if (lane < N_) {
                const float* epr = e_pT + ((size_t)(b0 + gw) * 128 + qw * 32) * NT_ + lane;
                const float* qp  = sGate + gw * 512;
                const int dd0 = qw * 32;
                for (int i = 0; i < 32; i += 2) {
                    ps0 += sPv[dd0 + i]     * ftanh_(qp[dd0 + i]     + epr[i * NT_]);
                    ps1 += sPv[dd0 + i + 1] * ftanh_(qp[dd0 + i + 1] + epr[(i + 1) * NT_]);
                }
            }
            sRed[w * 64 + lane] = ps0 + ps1;
        }
        __syncthreads();

        // ---- P6b: logits, log-softmax, argmax, MLP, outputs, next-x gather ----
        if (qw == 0) {
            const int g = gw;
            const int b = b0 + g;
            float u = sRed[(g * 4) * 64 + lane] + sRed[(g * 4 + 1) * 64 + lane]
                    + sRed[(g * 4 + 2) * 64 + lane] + sRed[(g * 4 + 3) * 64 + lane];
            const bool act = lane < N_;
            const unsigned long long mk = sMask[g];
            float logit;
            if (!act)                      logit = -__builtin_inff();
            else if ((mk >> lane) & 1ull)  logit = NEGV;
            else                           logit = 10.0f * ftanh_(u);
            float mx = wmax_(logit);
            float ex = act ? __expf(logit - mx) : 0.f;
            float s  = wsum_(ex);
            float lse = mx + __logf(s);
            if (act) outp[(size_t)b * (N_ * N_) + t * N_ + lane] = logit - lse;
            // argmax, first-index tie-break
            float av = logit; int ai = act ? lane : (N_ - 1);
#pragma unroll
            for (int mm = 1; mm < 64; mm <<= 1) {
                float ov = __shfl_xor(av, mm);
                int   oi = __shfl_xor(ai, mm);
                bool take = (ov > av) || (ov == av && oi < ai);
                av = take ? ov : av;
                ai = take ? oi : ai;
            }
            const int idx = ai;
            // time-prediction MLP: lane = hidden unit
            const int lastv = sLast[g];
            const float* Vl = V + ((size_t)b * N_ + lastv) * DV_;
            const float* Vi = V + ((size_t)b * N_ + idx) * DV_;
            float hacc = tpb1[lane];
#pragma unroll
            for (int k = 0; k < 8; ++k)  hacc += Vl[k] * tpW1[k * 64 + lane];
#pragma unroll
            for (int k = 0; k < 8; ++k)  hacc += Vi[k] * tpW1[(8 + k) * 64 + lane];
#pragma unroll
            for (int k = 0; k < 4; ++k)  hacc += sSF[g * 4 + k] * tpW1[(16 + k) * 64 + lane];
#pragma unroll
            for (int k = 0; k < 20; ++k) hacc += step_table[t * SE_ + k] * tpW1[(20 + k) * 64 + lane];
            hacc = fmaxf(hacc, 0.f);
            float pred = wsum_(hacc * tpW2[lane]) + tpb2[0];
            // next decoder input x = cu[idx, b, :] — idx is wave-uniform, loads broadcastable
            const float* xrow = cu + ((size_t)idx * B_ + b) * D_;
            sX[g * 128 + lane]      = xrow[lane];
            sX[g * 128 + 64 + lane] = xrow[64 + lane];
            if (lane == 0) {
                outp[(size_t)(B_ * N_) * N_ + (size_t)b * N_ + t]                         = (float)idx;
                outp[(size_t)(B_ * N_) * N_ + (size_t)(B_ * N_) + (size_t)b * N_ + t]     = pred;
                outp[(size_t)(B_ * N_) * N_ + 2 * (size_t)(B_ * N_) + (size_t)b * N_ + t] = pred;
                sPrev[g] = idx;
                sLast[g] = idx;
            }
        }
        __syncthreads();
    }
}

extern "C" void kernel_launch(void* const* d_in, const int* in_sizes, int n_in,
                              void* d_out, int out_size, void* d_ws, size_t ws_size,
                              hipStream_t stream)
{
    const float* dec   = (const float*)d_in[0];
    const float* h0    = (const float*)d_in[1];
    const float* c0    = (const float*)d_in[2];
    const unsigned char* vmask = (const unsigned char*)d_in[3];
    const int*   sidx  = (const int*)d_in[4];
    const float* V     = (const float*)d_in[5];
    const float* cu    = (const float*)d_in[8];
    const float* sfea  = (const float*)d_in[10];
    const float* W_ih  = (const float*)d_in[11];
    const float* W_hh  = (const float*)d_in[12];
    const float* b_ih  = (const float*)d_in[13];
    const float* b_hh  = (const float*)d_in[14];
    const float* gWq   = (const float*)d_in[15];
    const float* gbq   = (const float*)d_in[16];
    const float* gWr   = (const float*)d_in[17];
    const float* gbr   = (const float*)d_in[18];
    const float* gv    = (const float*)d_in[19];
    const float* pWq   = (const float*)d_in[20];
    const float* pbq   = (const float*)d_in[21];
    const float* pWr   = (const float*)d_in[22];
    const float* pbr   = (const float*)d_in[23];
    const float* pv    = (const float*)d_in[24];
    const float* stept = (const float*)d_in[25];
    const float* tpW1  = (const float*)d_in[26];
    const float* tpb1  = (const float*)d_in[27];
    const float* tpW2  = (const float*)d_in[28];
    const float* tpb2  = (const float*)d_in[29];

    float* e_g  = (float*)d_ws;                        // [B][N][D]      104.9 MB
    float* e_pT = e_g + (size_t)B_ * N_ * D_;          // [B][128][NT_]  134.2 MB

    // Precompute fixed attention keys (round-1 proven structure, two launches)
    proj_kernel <<<dim3(1024), 256, 0, stream>>>(gWr, gbr, cu, e_g);
    projT_kernel<<<dim3(1024), 256, 0, stream>>>(pWr, pbr, cu, e_pT);

    const size_t SMEM = 16408 * sizeof(float);   // 65,632 B -> 2 blocks/CU
    static int attr_done = 0;
    (void)hipFuncSetAttribute((const void*)decode_g2,
                              hipFuncAttributeMaxDynamicSharedMemorySize, (int)SMEM);
    (void)attr_done;

    decode_g2<<<dim3(B_ / 2), 512, SMEM, stream>>>(
        dec, h0, c0, vmask, sidx, V, cu, sfea,
        W_ih, W_hh, b_ih, b_hh, gWq, gbq, gv, pWq, pbq, pv,
        stept, tpW1, tpb1, tpW2, tpb2, e_g, e_pT, (float*)d_out);
}